// Round 9
// baseline (155.935 us; speedup 1.0000x reference)
//
#include <hip/hip_runtime.h>

typedef __attribute__((ext_vector_type(4))) float f32x4;
typedef __attribute__((ext_vector_type(4))) int   i32x4;
typedef __attribute__((ext_vector_type(8))) int   i32x8;

#define DIM 256
#define D4  64    // float4 per row

// sqrt(log2(e)/2): rows are normalized to THIS norm instead of 1, so the
// MFMA output is directly the exp2 argument (saves a v_mul per element in the
// gemm epilogue). 0.84932216^2 = 0.7213481 ~= log2(e)/2 (rel err 8e-7).
#define KSQRTC 0.84932216f

// One wave per row. Rows [0,N): exact fp32 pos_sim -> posPart[row] + scaled-
// normalized pk -> fp8 e4m3 (plain byte-k order). Rows [N,N+M): nv likewise.
__global__ __launch_bounds__(256) void normalize_kernel(
    const float4* __restrict__ pk, const float4* __restrict__ pv,
    const float4* __restrict__ nv, unsigned int* __restrict__ pkn,
    unsigned int* __restrict__ nvn, float* __restrict__ posPart, int N) {
  int row  = blockIdx.x * 4 + (threadIdx.x >> 6);
  int lane = threadIdx.x & 63;
  if (row < N) {
    float4 x = pk[row * D4 + lane];
    float4 y = pv[row * D4 + lane];
    float skk = x.x*x.x + x.y*x.y + x.z*x.z + x.w*x.w;
    float svv = y.x*y.x + y.y*y.y + y.z*y.z + y.w*y.w;
    float skv = x.x*y.x + x.y*y.y + x.z*y.z + x.w*y.w;
#pragma unroll
    for (int m = 32; m >= 1; m >>= 1) {
      skk += __shfl_xor(skk, m, 64);
      svv += __shfl_xor(svv, m, 64);
      skv += __shfl_xor(skv, m, 64);
    }
    float nk  = fmaxf(sqrtf(skk), 1e-8f);
    float nvv = fmaxf(sqrtf(svv), 1e-8f);
    if (lane == 0) posPart[row] = skv / (nk * nvv);
    float rk = KSQRTC / nk;
    int w = __builtin_amdgcn_cvt_pk_fp8_f32(x.x * rk, x.y * rk, 0, false);
    w = __builtin_amdgcn_cvt_pk_fp8_f32(x.z * rk, x.w * rk, w, true);
    pkn[(size_t)row * 64 + lane] = (unsigned int)w;
  } else {
    int r2 = row - N;
    float4 x = nv[r2 * D4 + lane];
    float s = x.x*x.x + x.y*x.y + x.z*x.z + x.w*x.w;
#pragma unroll
    for (int m = 32; m >= 1; m >>= 1) s += __shfl_xor(s, m, 64);
    float rn = KSQRTC / fmaxf(sqrtf(s), 1e-8f);
    int w = __builtin_amdgcn_cvt_pk_fp8_f32(x.x * rn, x.y * rn, 0, false);
    w = __builtin_amdgcn_cvt_pk_fp8_f32(x.z * rn, x.w * rn, w, true);
    nvn[(size_t)r2 * 64 + lane] = (unsigned int)w;
  }
}

// Fused fp8 GEMM (MX 16x16x128, unit scales = exact fp8) + exp2(acc) + row-sum.
// R9: NO LDS, NO barriers. R8's per-tile __syncthreads phase-locked the 4
// waves (epilogue VALU could never hide under another wave's MFMA). Now:
//  - A frags for the WG's 128-row stripe: persistent in VGPRs (64), loaded once.
//  - B frags: global->VGPR ping-pong at HALF-TILE granularity. The prefetch of
//    step s+1 is issued before step s's 16 MFMAs; its first USE is a step
//    later, so the loads are live across the MFMA block and the compiler
//    cannot sink them (R7's failure: immediately-used loads got sunk, VGPR=68,
//    serial load->wait->MFMA). Prefetch distance ~550cyc > ~250cyc L2 latency.
//  - Waves free-run (no barrier) -> natural desync lets epilogue VALU overlap
//    other waves' MFMA (m114 co-scheduling).
//  - rowpart accumulated in registers across all 8 tiles; ONE butterfly+store
//    per wave per kernel (R8 did 8 butterflies + 8 stores).
// WG 256 thr = 4 waves (2x2 of 64x64), tile 128x128, 8 col tiles per WG,
// grid (8 colgroups, 64 stripes) = 512 WGs = 2/CU.
__global__ __launch_bounds__(256, 2) void gemm_lse_kernel(
    const unsigned char* __restrict__ gA, const unsigned char* __restrict__ gB,
    float* __restrict__ partial, int N) {
  const int tid  = threadIdx.x;
  const int lane = tid & 63;
  const int wv   = tid >> 6;
  const int wm   = wv >> 1, wn = wv & 1;
  const int l15  = lane & 15, q = lane >> 4;
  const int row0 = blockIdx.y * 128;
  const int ct0  = blockIdx.x * 8;         // first col tile of this WG
  const int kUnitScale = 0x7F7F7F7F;       // e8m0 127 = 2^0 per byte

  // ---- A frags: 16 rows x (q*32 .. +32) per kb half; verified R7/R8 order ----
  const unsigned char* pa = gA + (size_t)(row0 + wm * 64 + l15) * 256 + q * 32;
  i32x4 alo[2][4], ahi[2][4];
#pragma unroll
  for (int kb = 0; kb < 2; kb++)
#pragma unroll
    for (int mi = 0; mi < 4; mi++) {
      alo[kb][mi] = *(const i32x4*)(pa + mi * 4096 + kb * 128);
      ahi[kb][mi] = *(const i32x4*)(pa + mi * 4096 + kb * 128 + 16);
    }

  // ---- B ping-pong: step s = (tile t = s>>1, half kb = s&1) ----
  // col = (ct0+t)*128 + wn*64 + ni*16 + l15; byte = col*256 + kb*128 + q*32
  const unsigned char* pb =
      gB + (size_t)(ct0 * 128 + wn * 64 + l15) * 256 + q * 32;
  i32x4 bbuf[2][8];
#pragma unroll
  for (int ni = 0; ni < 4; ni++) {          // prime step 0 (t=0, kb=0)
    bbuf[0][2 * ni]     = *(const i32x4*)(pb + ni * 4096);
    bbuf[0][2 * ni + 1] = *(const i32x4*)(pb + ni * 4096 + 16);
  }

  f32x4 acc[4][4];
#pragma unroll
  for (int mi = 0; mi < 4; mi++)
#pragma unroll
    for (int ni = 0; ni < 4; ni++) acc[mi][ni] = (f32x4){0.f, 0.f, 0.f, 0.f};

  float rp[4][4];
#pragma unroll
  for (int a = 0; a < 4; a++)
#pragma unroll
    for (int b = 0; b < 4; b++) rp[a][b] = 0.f;

#pragma unroll
  for (int s = 0; s < 16; s++) {
    const int kb = s & 1;
    // prefetch step s+1 into the other buffer (first use: next iteration)
    if (s < 15) {
      const int t2 = (s + 1) >> 1, kb2 = (s + 1) & 1;
      const unsigned char* p2 = pb + t2 * 32768 + kb2 * 128;
#pragma unroll
      for (int ni = 0; ni < 4; ni++) {
        bbuf[(s + 1) & 1][2 * ni]     = *(const i32x4*)(p2 + ni * 4096);
        bbuf[(s + 1) & 1][2 * ni + 1] = *(const i32x4*)(p2 + ni * 4096 + 16);
      }
    }
    // 16 MFMAs of this half-tile
#pragma unroll
    for (int mi = 0; mi < 4; mi++) {
      i32x8 af = (i32x8){alo[kb][mi].x, alo[kb][mi].y, alo[kb][mi].z, alo[kb][mi].w,
                         ahi[kb][mi].x, ahi[kb][mi].y, ahi[kb][mi].z, ahi[kb][mi].w};
#pragma unroll
      for (int ni = 0; ni < 4; ni++) {
        i32x4 lo = bbuf[s & 1][2 * ni], hi = bbuf[s & 1][2 * ni + 1];
        i32x8 bf = (i32x8){lo.x, lo.y, lo.z, lo.w, hi.x, hi.y, hi.z, hi.w};
        acc[mi][ni] = __builtin_amdgcn_mfma_scale_f32_16x16x128_f8f6f4(
            af, bf, acc[mi][ni],
            0, 0,                      // cbsz/blgp = fp8 e4m3
            0, kUnitScale, 0, kUnitScale);
      }
    }
    // tile finished (kb==1): epilogue exp2 (scale pre-folded into norms),
    // accumulate into rowpart, reset acc. No shuffles here.
    if (kb == 1) {
#pragma unroll
      for (int mi = 0; mi < 4; mi++)
#pragma unroll
        for (int ni = 0; ni < 4; ni++) {
#pragma unroll
          for (int rr = 0; rr < 4; rr++)
            rp[mi][rr] += __builtin_amdgcn_exp2f(acc[mi][ni][rr]);
          acc[mi][ni] = (f32x4){0.f, 0.f, 0.f, 0.f};
        }
    }
  }

  // ---- single butterfly + one dense coalesced 256B store per wave ----
  // C/D layout (verified R2-R8): col = lane&15, row = quad*4 + rr.
  float keep = 0.f;
#pragma unroll
  for (int mi = 0; mi < 4; mi++)
#pragma unroll
    for (int rr = 0; rr < 4; rr++) {
      float v = rp[mi][rr];
      v += __shfl_xor(v, 1, 16);
      v += __shfl_xor(v, 2, 16);
      v += __shfl_xor(v, 4, 16);
      v += __shfl_xor(v, 8, 16);
      if (l15 == mi * 4 + rr) keep = v;
    }
  int lrow = (l15 >> 2) * 16 + q * 4 + (l15 & 3);
  partial[(size_t)(blockIdx.x * 2 + wn) * N + row0 + wm * 64 + lrow] = keep;
}

// out = mean(ln(sum_j partial[j][row])) - 0.5*mean(posPart). 16 slabs now.
__global__ __launch_bounds__(256) void finalize_kernel(
    const float* __restrict__ partial, const float* __restrict__ posPart,
    float* __restrict__ out, int N, int slabsPerGroup, float invN) {
  __shared__ float red[4][64];
  int t  = threadIdx.x;
  int rl = t & 63, g = t >> 6;
  int row = blockIdx.x * 64 + rl;
  const float* p = partial + (size_t)(g * slabsPerGroup) * N + row;
  float s = 0.f;
#pragma unroll 4
  for (int j = 0; j < slabsPerGroup; j++) s += p[(size_t)j * N];
  red[g][rl] = s;
  __syncthreads();
  if (t < 64) {
    float tot = red[0][rl] + red[1][rl] + red[2][rl] + red[3][rl];
    float v = __builtin_amdgcn_logf(tot) * 0.69314718055994531f
              - 0.5f * posPart[row];
#pragma unroll
    for (int m = 32; m >= 1; m >>= 1) v += __shfl_xor(v, m, 64);
    if (rl == 0) atomicAdd(out, v * invN);
  }
}

extern "C" void kernel_launch(void* const* d_in, const int* in_sizes, int n_in,
                              void* d_out, int out_size, void* d_ws, size_t ws_size,
                              hipStream_t stream) {
  const float* pk = (const float*)d_in[0];
  const float* pv = (const float*)d_in[1];
  const float* nv = (const float*)d_in[2];
  int N = in_sizes[0] / DIM;   // 8192
  int M = in_sizes[2] / DIM;   // 8192
  float* out = (float*)d_out;

  unsigned char* pkn = (unsigned char*)d_ws;                   // [N,256] fp8
  unsigned char* nvn = pkn + (size_t)N * DIM;                  // [M,256] fp8
  float* partial = (float*)(nvn + (size_t)M * DIM);            // [16][N] fp32
  float* posPart = partial + (size_t)16 * N;                   // [N] fp32

  hipMemsetAsync(out, 0, sizeof(float), stream);

  normalize_kernel<<<(N + M) / 4, 256, 0, stream>>>(
      (const float4*)pk, (const float4*)pv, (const float4*)nv,
      (unsigned int*)pkn, (unsigned int*)nvn, posPart, N);

  gemm_lse_kernel<<<dim3(M / (128 * 8), N / 128), 256, 0, stream>>>(
      pkn, nvn, partial, N);

  finalize_kernel<<<N / 64, 256, 0, stream>>>(
      partial, posPart, out, N, 4, 1.0f / (float)N);
}